// Round 2
// baseline (2012.915 us; speedup 1.0000x reference)
//
#include <hip/hip_runtime.h>
#include <hip/hip_bf16.h>
#include <stdint.h>

// Problem constants
#define B_  4
#define S_  2048
#define D_  2048
#define H_  16
#define DH_ 128
#define FF_ 8192

typedef __bf16 bf16x8 __attribute__((ext_vector_type(8)));
typedef __bf16 bf16x4 __attribute__((ext_vector_type(4)));
typedef __bf16 bf16x2 __attribute__((ext_vector_type(2)));
typedef float  f32x4  __attribute__((ext_vector_type(4)));

__device__ __forceinline__ void gll16(const void* g, void* l) {
    __builtin_amdgcn_global_load_lds(
        (const __attribute__((address_space(1))) void*)(g),
        (__attribute__((address_space(3))) void*)(l), 16, 0, 0);
}

// ---------------------------------------------------------------------------
// fp32 -> bf16 elementwise conversion (vectorized float4 -> 4x bf16)
// ---------------------------------------------------------------------------
__global__ void f2b_kernel(const float* __restrict__ in, __bf16* __restrict__ out, int n)
{
    int i = blockIdx.x * blockDim.x + threadIdx.x;
    int stride = gridDim.x * blockDim.x;
    for (int j = i; j * 4 < n; j += stride) {
        float4 v = *(const float4*)(in + (size_t)j * 4);
        bf16x4 o = {(__bf16)v.x, (__bf16)v.y, (__bf16)v.z, (__bf16)v.w};
        *(bf16x4*)(out + (size_t)j * 4) = o;
    }
}

// ---------------------------------------------------------------------------
// GEMM: C[M,N] = A[M,K] * B[N,K]^T + bias   (A,B bf16 row-major, fp32 acc)
// 128x128 tile, BK=32, 4 waves (2x2), mfma_f32_16x16x32_bf16, bf16 out.
// ---------------------------------------------------------------------------
template<bool RELU>
__global__ __launch_bounds__(256)
void gemm_bt(const __bf16* __restrict__ A, const __bf16* __restrict__ Bw,
             const float* __restrict__ bias, __bf16* __restrict__ Cout,
             int M, int N, int K)
{
    __shared__ __align__(16) __bf16 As[128 * 32];
    __shared__ __align__(16) __bf16 Bs[128 * 32];

    const int tid  = threadIdx.x;
    const int lane = tid & 63;
    const int w    = tid >> 6;
    const int wr   = w >> 1, wc = w & 1;
    const int m0   = blockIdx.y << 7;
    const int n0   = blockIdx.x << 7;

    f32x4 zero = {0.f, 0.f, 0.f, 0.f};
    f32x4 acc[4][4];
#pragma unroll
    for (int m = 0; m < 4; ++m)
#pragma unroll
        for (int n = 0; n < 4; ++n) acc[m][n] = zero;

    // staging: each wave loads chunks 2w, 2w+1 of A-tile and B-tile
    const int srow = lane >> 2;          // 0..15
    const int scol = (lane & 3) << 3;    // 0,8,16,24
    const int c0 = 2 * w, c1 = 2 * w + 1;
    const __bf16* gA0 = A  + (size_t)(m0 + c0 * 16 + srow) * K + scol;
    const __bf16* gA1 = A  + (size_t)(m0 + c1 * 16 + srow) * K + scol;
    const __bf16* gB0 = Bw + (size_t)(n0 + c0 * 16 + srow) * K + scol;
    const __bf16* gB1 = Bw + (size_t)(n0 + c1 * 16 + srow) * K + scol;
    __bf16* lA0 = &As[c0 * 512 + lane * 8];
    __bf16* lA1 = &As[c1 * 512 + lane * 8];
    __bf16* lB0 = &Bs[c0 * 512 + lane * 8];
    __bf16* lB1 = &Bs[c1 * 512 + lane * 8];

    const int fr = lane & 15;            // fragment row
    const int kg = (lane >> 4) << 3;     // k-group offset (0,8,16,24)

    for (int k0 = 0; k0 < K; k0 += 32) {
        gll16(gA0 + k0, lA0);
        gll16(gA1 + k0, lA1);
        gll16(gB0 + k0, lB0);
        gll16(gB1 + k0, lB1);
        __syncthreads();   // drains vmcnt -> LDS tiles ready

        bf16x8 af[4], bfr[4];
#pragma unroll
        for (int m = 0; m < 4; ++m)
            af[m] = *(const bf16x8*)&As[(wr * 64 + m * 16 + fr) * 32 + kg];
#pragma unroll
        for (int n = 0; n < 4; ++n)
            bfr[n] = *(const bf16x8*)&Bs[(wc * 64 + n * 16 + fr) * 32 + kg];
#pragma unroll
        for (int m = 0; m < 4; ++m)
#pragma unroll
            for (int n = 0; n < 4; ++n)
                acc[m][n] = __builtin_amdgcn_mfma_f32_16x16x32_bf16(
                                af[m], bfr[n], acc[m][n], 0, 0, 0);
        __syncthreads();
    }

    // epilogue: C/D layout col = lane&15, row = (lane>>4)*4 + reg
    const int fq = lane >> 4;
#pragma unroll
    for (int m = 0; m < 4; ++m) {
#pragma unroll
        for (int n = 0; n < 4; ++n) {
            const int col = n0 + wc * 64 + n * 16 + fr;
            const float bv = bias[col];
#pragma unroll
            for (int r = 0; r < 4; ++r) {
                const int row = m0 + wr * 64 + m * 16 + fq * 4 + r;
                float v = acc[m][n][r] + bv;
                if (RELU) v = fmaxf(v, 0.f);
                Cout[(size_t)row * N + col] = (__bf16)v;
            }
        }
    }
}

// ---------------------------------------------------------------------------
// Per-head LayerNorm over DH=128 (qk-norm), in-place on bf16, scale folded.
// 4 waves/block, one wave per 128-element row.
// ---------------------------------------------------------------------------
__global__ __launch_bounds__(256)
void qk_norm_ip(__bf16* __restrict__ data, float scale)
{
    const int row = blockIdx.x * 4 + (threadIdx.x >> 6);
    const int t   = threadIdx.x & 63;
    const size_t base = (size_t)row * DH_;
    bf16x2 v2 = *(bf16x2*)(data + base + t * 2);
    const float a = (float)v2[0], b = (float)v2[1];
    float s  = a + b;
    float s2 = a * a + b * b;
#pragma unroll
    for (int o = 32; o; o >>= 1) { s += __shfl_xor(s, o); s2 += __shfl_xor(s2, o); }
    const float mean = s * (1.f / DH_);
    const float var  = s2 * (1.f / DH_) - mean * mean;
    const float rstd = rsqrtf(var + 1e-5f) * scale;
    bf16x2 o2 = {(__bf16)((a - mean) * rstd), (__bf16)((b - mean) * rstd)};
    *(bf16x2*)(data + base + t * 2) = o2;
}

// ---------------------------------------------------------------------------
// add_ln_x: x (fp32) + a (bf16) -> LN -> bf16 out.  One block per row.
// ---------------------------------------------------------------------------
__global__ __launch_bounds__(256)
void add_ln_x(const float* __restrict__ X, const __bf16* __restrict__ A2,
              __bf16* __restrict__ outb)
{
    __shared__ float ls[4], ls2[4];
    const int row = blockIdx.x;
    const int t   = threadIdx.x;
    const size_t base = (size_t)row * D_;

    float4 a = *(const float4*)(X + base + t * 8);
    float4 b = *(const float4*)(X + base + t * 8 + 4);
    bf16x8 c8 = *(const bf16x8*)(A2 + base + t * 8);
    float v[8] = {a.x + (float)c8[0], a.y + (float)c8[1], a.z + (float)c8[2], a.w + (float)c8[3],
                  b.x + (float)c8[4], b.y + (float)c8[5], b.z + (float)c8[6], b.w + (float)c8[7]};
    float s = 0.f, s2 = 0.f;
#pragma unroll
    for (int i = 0; i < 8; ++i) { s += v[i]; s2 += v[i] * v[i]; }
#pragma unroll
    for (int o = 32; o; o >>= 1) { s += __shfl_xor(s, o); s2 += __shfl_xor(s2, o); }
    const int w = t >> 6;
    if ((t & 63) == 0) { ls[w] = s; ls2[w] = s2; }
    __syncthreads();
    s  = ls[0] + ls[1] + ls[2] + ls[3];
    s2 = ls2[0] + ls2[1] + ls2[2] + ls2[3];
    const float mean = s * (1.f / D_);
    const float var  = s2 * (1.f / D_) - mean * mean;
    const float rstd = rsqrtf(var + 1e-5f);

    bf16x8 ob;
#pragma unroll
    for (int i = 0; i < 8; ++i) ob[i] = (__bf16)((v[i] - mean) * rstd);
    *(bf16x8*)(outb + base + t * 8) = ob;
}

// ---------------------------------------------------------------------------
// add_ln_f: x1 (bf16) + f2 (bf16) -> LN -> fp32 out.  One block per row.
// ---------------------------------------------------------------------------
__global__ __launch_bounds__(256)
void add_ln_f(const __bf16* __restrict__ X, const __bf16* __restrict__ A2,
              float* __restrict__ outf)
{
    __shared__ float ls[4], ls2[4];
    const int row = blockIdx.x;
    const int t   = threadIdx.x;
    const size_t base = (size_t)row * D_;

    bf16x8 a8 = *(const bf16x8*)(X  + base + t * 8);
    bf16x8 c8 = *(const bf16x8*)(A2 + base + t * 8);
    float v[8];
#pragma unroll
    for (int i = 0; i < 8; ++i) v[i] = (float)a8[i] + (float)c8[i];
    float s = 0.f, s2 = 0.f;
#pragma unroll
    for (int i = 0; i < 8; ++i) { s += v[i]; s2 += v[i] * v[i]; }
#pragma unroll
    for (int o = 32; o; o >>= 1) { s += __shfl_xor(s, o); s2 += __shfl_xor(s2, o); }
    const int w = t >> 6;
    if ((t & 63) == 0) { ls[w] = s; ls2[w] = s2; }
    __syncthreads();
    s  = ls[0] + ls[1] + ls[2] + ls[3];
    s2 = ls2[0] + ls2[1] + ls2[2] + ls2[3];
    const float mean = s * (1.f / D_);
    const float var  = s2 * (1.f / D_) - mean * mean;
    const float rstd = rsqrtf(var + 1e-5f);

    float4 o0 = {(v[0] - mean) * rstd, (v[1] - mean) * rstd,
                 (v[2] - mean) * rstd, (v[3] - mean) * rstd};
    float4 o1 = {(v[4] - mean) * rstd, (v[5] - mean) * rstd,
                 (v[6] - mean) * rstd, (v[7] - mean) * rstd};
    *(float4*)(outf + base + t * 8)     = o0;
    *(float4*)(outf + base + t * 8 + 4) = o1;
}

// ---------------------------------------------------------------------------
// Flash attention (causal). Block = 64 q rows (4 waves x 16), 32-key tiles.
// Q pre-scaled by 1/sqrt(DH). Q,K,V bf16 [B*S][D], head h at cols h*128..+127.
// ---------------------------------------------------------------------------
__global__ __launch_bounds__(256)
void attn_fwd(const __bf16* __restrict__ Q, const __bf16* __restrict__ K,
              const __bf16* __restrict__ V, __bf16* __restrict__ O)
{
    __shared__ __align__(16) __bf16 Vt[128 * 40];   // V^T, padded
    __shared__ __align__(16) __bf16 Pl[4][16 * 32]; // per-wave P tile

    const int tid  = threadIdx.x;
    const int lane = tid & 63;
    const int w    = tid >> 6;
    const int qt = blockIdx.x, h = blockIdx.y, b = blockIdx.z;
    const int q0 = qt * 64 + w * 16;
    const int fr = lane & 15, fq = lane >> 4;
    const size_t hb = ((size_t)b * S_) * D_ + (size_t)h * DH_;

    bf16x8 qf[4];
#pragma unroll
    for (int ds = 0; ds < 4; ++ds)
        qf[ds] = *(const bf16x8*)(Q + hb + (size_t)(q0 + fr) * D_ + ds * 32 + fq * 8);

    f32x4 zero = {0.f, 0.f, 0.f, 0.f};
    f32x4 cacc[8];
#pragma unroll
    for (int dt = 0; dt < 8; ++dt) cacc[dt] = zero;
    float mrow[4] = {-1e30f, -1e30f, -1e30f, -1e30f};
    float lrow[4] = {0.f, 0.f, 0.f, 0.f};

    const int kk = tid & 31, dseg = tid >> 5;
    const int nkt = qt * 2 + 2;

    for (int kt = 0; kt < nkt; ++kt) {
        {   // stage V^T
            const __bf16* vp = V + hb + (size_t)(kt * 32 + kk) * D_ + dseg * 16;
            bf16x8 v0 = *(const bf16x8*)vp;
            bf16x8 v1 = *(const bf16x8*)(vp + 8);
#pragma unroll
            for (int i = 0; i < 8; ++i) Vt[(dseg * 16 + i) * 40 + kk] = v0[i];
#pragma unroll
            for (int i = 0; i < 8; ++i) Vt[(dseg * 16 + 8 + i) * 40 + kk] = v1[i];
        }
        __syncthreads();

        if (kt * 32 <= q0 + 15) {   // wave-uniform predicate
            f32x4 sa[2];
#pragma unroll
            for (int hk = 0; hk < 2; ++hk) {
                f32x4 s = zero;
                const __bf16* kp = K + hb + (size_t)(kt * 32 + hk * 16 + fr) * D_ + fq * 8;
#pragma unroll
                for (int ds = 0; ds < 4; ++ds) {
                    bf16x8 kf = *(const bf16x8*)(kp + ds * 32);
                    s = __builtin_amdgcn_mfma_f32_16x16x32_bf16(qf[ds], kf, s, 0, 0, 0);
                }
                sa[hk] = s;
            }
#pragma unroll
            for (int r = 0; r < 4; ++r) {
                const int qi = q0 + fq * 4 + r;
                float s0 = (kt * 32 + fr      <= qi) ? sa[0][r] : -1e30f;
                float s1 = (kt * 32 + 16 + fr <= qi) ? sa[1][r] : -1e30f;
                float mx = fmaxf(s0, s1);
#pragma unroll
                for (int o = 1; o < 16; o <<= 1) mx = fmaxf(mx, __shfl_xor(mx, o));
                const float mnew = fmaxf(mrow[r], mx);
                const float corr = __expf(mrow[r] - mnew);
                const float p0 = __expf(s0 - mnew);
                const float p1 = __expf(s1 - mnew);
                float rs = p0 + p1;
#pragma unroll
                for (int o = 1; o < 16; o <<= 1) rs += __shfl_xor(rs, o);
                lrow[r] = lrow[r] * corr + rs;
                mrow[r] = mnew;
#pragma unroll
                for (int dt = 0; dt < 8; ++dt) cacc[dt][r] *= corr;
                Pl[w][(fq * 4 + r) * 32 + fr]      = (__bf16)p0;
                Pl[w][(fq * 4 + r) * 32 + 16 + fr] = (__bf16)p1;
            }
            bf16x8 pf = *(const bf16x8*)&Pl[w][fr * 32 + fq * 8];
#pragma unroll
            for (int dt = 0; dt < 8; ++dt) {
                bf16x8 vf = *(const bf16x8*)&Vt[(dt * 16 + fr) * 40 + fq * 8];
                cacc[dt] = __builtin_amdgcn_mfma_f32_16x16x32_bf16(pf, vf, cacc[dt], 0, 0, 0);
            }
        }
        __syncthreads();
    }

#pragma unroll
    for (int dt = 0; dt < 8; ++dt) {
#pragma unroll
        for (int r = 0; r < 4; ++r) {
            const int qi = q0 + fq * 4 + r;
            const float o = cacc[dt][r] / lrow[r];
            O[hb + (size_t)qi * D_ + dt * 16 + fr] = (__bf16)o;
        }
    }
}

// ---------------------------------------------------------------------------
// launch — total workspace use: exactly 256 MiB
// ---------------------------------------------------------------------------
extern "C" void kernel_launch(void* const* d_in, const int* in_sizes, int n_in,
                              void* d_out, int out_size, void* d_ws, size_t ws_size,
                              hipStream_t stream)
{
    const float* x  = (const float*)d_in[0];
    const float* Wq = (const float*)d_in[2];  const float* bq = (const float*)d_in[3];
    const float* Wk = (const float*)d_in[4];  const float* bk = (const float*)d_in[5];
    const float* Wv = (const float*)d_in[6];  const float* bv = (const float*)d_in[7];
    const float* Wo = (const float*)d_in[8];  const float* bo = (const float*)d_in[9];
    const float* W1 = (const float*)d_in[10]; const float* b1 = (const float*)d_in[11];
    const float* W2 = (const float*)d_in[12]; const float* b2 = (const float*)d_in[13];
    float* out = (float*)d_out;

    const size_t NT  = (size_t)B_ * S_;            // 8192 rows
    const size_t MB  = 1024 * 1024;
    const size_t NEED = 256 * MB;
    if (ws_size < NEED) return;   // graceful fail -> absmax error, not a fault

    uint8_t* ws = (uint8_t*)d_ws;
    __bf16* Wb   = (__bf16*)(ws);              // 32 MiB: weight staging (reused 6x)
    __bf16* xb   = (__bf16*)(ws + 32  * MB);   // 32 MiB: x bf16; later x1b
    __bf16* vb   = (__bf16*)(ws + 64  * MB);   // 32 MiB: V
    __bf16* fb   = (__bf16*)(ws + 96  * MB);   // 32 MiB: attn_out bf16; later f2 bf16
    __bf16* h1   = (__bf16*)(ws + 128 * MB);   // 128 MiB: FF hidden; hosts K/Q/ctx early
    __bf16* kb   = h1;                          // 32 MiB (dead before FF1)
    __bf16* qb   = h1 + 16 * MB;                // 32 MiB (bf16 elems: +32 MiB bytes)
    __bf16* ctxb = h1 + 32 * MB;                // 32 MiB
    __bf16* x1b  = xb;                          // xb dead after V projection

    const dim3 blk(256);
    const dim3 gD(D_ / 128, NT / 128);     // (16, 64)
    const dim3 gF(FF_ / 128, NT / 128);    // (64, 64)

    // x -> bf16
    f2b_kernel<<<2048, 256, 0, stream>>>(x, xb, (int)(NT * D_));

    // QKV projections (weight converted right before each GEMM, shared buffer)
    f2b_kernel<<<1024, 256, 0, stream>>>(Wq, Wb, D_ * D_);
    gemm_bt<false><<<gD, blk, 0, stream>>>(xb, Wb, bq, qb, (int)NT, D_, D_);
    f2b_kernel<<<1024, 256, 0, stream>>>(Wk, Wb, D_ * D_);
    gemm_bt<false><<<gD, blk, 0, stream>>>(xb, Wb, bk, kb, (int)NT, D_, D_);
    f2b_kernel<<<1024, 256, 0, stream>>>(Wv, Wb, D_ * D_);
    gemm_bt<false><<<gD, blk, 0, stream>>>(xb, Wb, bv, vb, (int)NT, D_, D_);

    // qk-norm in-place (per-head LN over 128), 1/sqrt(DH) folded into Q
    qk_norm_ip<<<(int)(NT * H_ / 4), blk, 0, stream>>>(qb, 0.08838834764831845f);
    qk_norm_ip<<<(int)(NT * H_ / 4), blk, 0, stream>>>(kb, 1.0f);

    // causal flash attention
    attn_fwd<<<dim3(S_ / 64, H_, B_), blk, 0, stream>>>(qb, kb, vb, ctxb);

    // output projection + residual + LN -> x1b (bf16)
    f2b_kernel<<<1024, 256, 0, stream>>>(Wo, Wb, D_ * D_);
    gemm_bt<false><<<gD, blk, 0, stream>>>(ctxb, Wb, bo, fb, (int)NT, D_, D_);
    add_ln_x<<<(int)NT, blk, 0, stream>>>(x, fb, x1b);

    // FFN (h1 overwrites K/Q/ctx region -- all dead now)
    f2b_kernel<<<2048, 256, 0, stream>>>(W1, Wb, FF_ * D_);
    gemm_bt<true><<<gF, blk, 0, stream>>>(x1b, Wb, b1, h1, (int)NT, FF_, D_);
    f2b_kernel<<<2048, 256, 0, stream>>>(W2, Wb, D_ * FF_);
    gemm_bt<false><<<gD, blk, 0, stream>>>(h1, Wb, b2, fb, (int)NT, D_, FF_);

    // final residual + LN -> fp32 out
    add_ln_f<<<(int)NT, blk, 0, stream>>>(x1b, fb, out);
}